// Round 6
// baseline (261.730 us; speedup 1.0000x reference)
//
#include <hip/hip_runtime.h>

#define LL  210      // window length
#define MM  55       // channels
#define NBM 440      // B*M
#define DM  256      // d_model
#define MLT 11550    // MM*LL
#define BLM 92400    // B*LL*MM (one output slab)

// ws layout (floats):
#define XTG_OFF  0        // 55 grps * 210 pos * 8 series = 92400
#define W1T_OFF  92400    // 259 transposed cols * 256 = 66304
#define REC_OFF  158704   // ksize packed records = 5120
// w1t column offsets: num0=0(69), num1=69(41), num2=110(29),
//                     ss0=139(24), ss1=163(36), ns0=199(36), ns1=235(24)

__device__ __forceinline__ void fma4(float4& a, const float4 w, const float s) {
    a.x += w.x * s; a.y += w.y * s; a.z += w.z * s; a.w += w.w * s;
}
__device__ __forceinline__ void fms4(float4& a, const float4 w, const float s) {
    a.x -= w.x * s; a.y -= w.y * s; a.z -= w.z * s; a.w -= w.w * s;
}

// 8 simultaneous 64-lane reductions: returns sum over all lanes of y[lane&7]
__device__ __forceinline__ float bfly8(const float y[8], const int lane) {
    float z[4];
#pragma unroll
    for (int i = 0; i < 4; ++i) {
        float snd = (lane & 1) ? y[2*i] : y[2*i+1];
        float rcv = __shfl_xor(snd, 1, 64);
        z[i] = ((lane & 1) ? y[2*i+1] : y[2*i]) + rcv;
    }
    float u[2];
#pragma unroll
    for (int i = 0; i < 2; ++i) {
        float snd = (lane & 2) ? z[2*i] : z[2*i+1];
        float rcv = __shfl_xor(snd, 2, 64);
        u[i] = ((lane & 2) ? z[2*i+1] : z[2*i]) + rcv;
    }
    {
        float snd = (lane & 4) ? u[0] : u[1];
        float rcv = __shfl_xor(snd, 4, 64);
        float w = ((lane & 4) ? u[1] : u[0]) + rcv;
        w += __shfl_xor(w, 8, 64);
        w += __shfl_xor(w, 16, 64);
        w += __shfl_xor(w, 32, 64);
        return w;
    }
}

// ---------- prep: RevIN (grp-tiled, coalesced) -> xtg; transpose W1s; pack records ----------
__global__ __launch_bounds__(256) void kprep(
        const float* __restrict__ x,
        const float* __restrict__ nw0, const float* __restrict__ nw1, const float* __restrict__ nw2,
        const float* __restrict__ ssw0, const float* __restrict__ ssw1,
        const float* __restrict__ nsw0, const float* __restrict__ nsw1,
        const float* __restrict__ s1W0, const float* __restrict__ s1b0, const float* __restrict__ s2W0,
        const float* __restrict__ s1W1, const float* __restrict__ s1b1, const float* __restrict__ s2W1,
        const float* __restrict__ s1W2, const float* __restrict__ s1b2, const float* __restrict__ s2W2,
        float* __restrict__ xtg, float* __restrict__ w1t, float* __restrict__ recs) {
    const int t = threadIdx.x;
    const int blk = blockIdx.x;
    if (blk < 55) {
        // one grp of 8 series; thread = (li, mi); values kept in registers
        const int mi = t & 7, li = t >> 3;           // li in [0,32)
        const int bm = blk * 8 + mi;
        const int b = bm / MM, m = bm - b * MM;
        const float* xp = x + b * MLT + m;
        float vr[7], s1 = 0.f, s2 = 0.f;
#pragma unroll
        for (int it = 0; it < 7; ++it) {
            const int l = li + 32 * it;
            const float v = (l < LL) ? xp[l * MM] : 0.f;
            vr[it] = v; s1 += v; s2 += v * v;
        }
        s1 += __shfl_xor(s1, 8, 64);  s2 += __shfl_xor(s2, 8, 64);
        s1 += __shfl_xor(s1, 16, 64); s2 += __shfl_xor(s2, 16, 64);
        s1 += __shfl_xor(s1, 32, 64); s2 += __shfl_xor(s2, 32, 64);
        __shared__ float red[2][4][8];
        const int wid = t >> 6, lane = t & 63;
        if (lane < 8) { red[0][wid][lane] = s1; red[1][wid][lane] = s2; }
        __syncthreads();
        const float S1 = red[0][0][mi] + red[0][1][mi] + red[0][2][mi] + red[0][3][mi];
        const float S2 = red[1][0][mi] + red[1][1][mi] + red[1][2][mi] + red[1][3][mi];
        const float mean = S1 * (1.f / 210.f);
        const float inv = rsqrtf(S2 * (1.f / 210.f) - mean * mean + 1e-5f);
        float* xo = xtg + blk * 1680 + mi;
#pragma unroll
        for (int it = 0; it < 7; ++it) {
            const int l = li + 32 * it;
            if (l < LL) xo[l * 8] = (vr[it] - mean) * inv;
        }
    } else if (blk < 55 + 259) {
        const int e = (blk - 55) * 256 + t;   // [0, 259*256)
        const int cg = e >> 8, d = e & 255;
        const float* src; int ind, c;
        if (cg < 69)       { src = nw0;  ind = 69; c = cg; }
        else if (cg < 110) { src = nw1;  ind = 41; c = cg - 69; }
        else if (cg < 139) { src = nw2;  ind = 29; c = cg - 110; }
        else if (cg < 163) { src = ssw0; ind = 24; c = cg - 139; }
        else if (cg < 199) { src = ssw1; ind = 36; c = cg - 163; }
        else if (cg < 235) { src = nsw0; ind = 36; c = cg - 199; }
        else               { src = nsw1; ind = 24; c = cg - 235; }
        w1t[cg * DM + d] = src[d * ind + c];
    } else {
        const int e = (blk - 55 - 259) * 256 + t;   // [0, 5120)
        float v;
        if (e < 1024) {
            int d = e >> 2, c = e & 3;
            v = (c < 2) ? s1W0[d * 2 + c] : (c == 2 ? s1b0[d] : s2W0[d]);
        } else if (e < 3072) {
            int rel = e - 1024, d = rel >> 3, c = rel & 7;
            v = (c < 4) ? s1W1[d * 4 + c] : (c == 4 ? s1b1[d] : (c == 5 ? s2W1[d] : 0.f));
        } else {
            int rel = e - 3072, d = rel >> 3, c = rel & 7;
            v = (c < 6) ? s1W2[d * 6 + c] : (c == 6 ? s1b2[d] : s2W2[d]);
        }
        recs[e] = v;
    }
}

// ---------- size branches: thread-per-output, G=4 series per block ----------
template <int IND>
__device__ __forceinline__ void ksize_body4(const float* __restrict__ xtg,
        const float* __restrict__ rec, const float* __restrict__ b2,
        int bm0, int j, float* __restrict__ out) {
    constexpr int N = LL / (IND + 1);
    const int t = threadIdx.x;
    if (t >= LL) return;
    const float* xs = xtg + (bm0 >> 3) * 1680 + (bm0 & 7);
    const int i = t / N, k = t - i * N;
    float4 f[IND];
#pragma unroll
    for (int idx = 0; idx < IND; ++idx) {
        const int row = idx + (idx >= i);
        f[idx] = *(const float4*)&xs[(row * N + k) * 8];
    }
    const float b2v = b2[0];
    float4 ya = make_float4(0.f,0.f,0.f,0.f), yb = ya;
    const float4* r4 = (const float4*)rec;
    if constexpr (IND == 2) {
#pragma unroll 4
        for (int d = 0; d < DM; d += 2) {
            const float4 a = r4[d], b = r4[d + 1];
            ya.x += fmaxf(a.x*f[0].x + a.y*f[1].x + a.z, 0.f) * a.w;
            ya.y += fmaxf(a.x*f[0].y + a.y*f[1].y + a.z, 0.f) * a.w;
            ya.z += fmaxf(a.x*f[0].z + a.y*f[1].z + a.z, 0.f) * a.w;
            ya.w += fmaxf(a.x*f[0].w + a.y*f[1].w + a.z, 0.f) * a.w;
            yb.x += fmaxf(b.x*f[0].x + b.y*f[1].x + b.z, 0.f) * b.w;
            yb.y += fmaxf(b.x*f[0].y + b.y*f[1].y + b.z, 0.f) * b.w;
            yb.z += fmaxf(b.x*f[0].z + b.y*f[1].z + b.z, 0.f) * b.w;
            yb.w += fmaxf(b.x*f[0].w + b.y*f[1].w + b.z, 0.f) * b.w;
        }
    } else if constexpr (IND == 4) {
#pragma unroll 4
        for (int d = 0; d < DM; d += 2) {
            const float4 a = r4[2*d], b = r4[2*d+1];
            const float4 c = r4[2*d+2], e = r4[2*d+3];
            ya.x += fmaxf(a.x*f[0].x + a.y*f[1].x + a.z*f[2].x + a.w*f[3].x + b.x, 0.f) * b.y;
            ya.y += fmaxf(a.x*f[0].y + a.y*f[1].y + a.z*f[2].y + a.w*f[3].y + b.x, 0.f) * b.y;
            ya.z += fmaxf(a.x*f[0].z + a.y*f[1].z + a.z*f[2].z + a.w*f[3].z + b.x, 0.f) * b.y;
            ya.w += fmaxf(a.x*f[0].w + a.y*f[1].w + a.z*f[2].w + a.w*f[3].w + b.x, 0.f) * b.y;
            yb.x += fmaxf(c.x*f[0].x + c.y*f[1].x + c.z*f[2].x + c.w*f[3].x + e.x, 0.f) * e.y;
            yb.y += fmaxf(c.x*f[0].y + c.y*f[1].y + c.z*f[2].y + c.w*f[3].y + e.x, 0.f) * e.y;
            yb.z += fmaxf(c.x*f[0].z + c.y*f[1].z + c.z*f[2].z + c.w*f[3].z + e.x, 0.f) * e.y;
            yb.w += fmaxf(c.x*f[0].w + c.y*f[1].w + c.z*f[2].w + c.w*f[3].w + e.x, 0.f) * e.y;
        }
    } else {
#pragma unroll 4
        for (int d = 0; d < DM; d += 2) {
            const float4 a = r4[2*d], b = r4[2*d+1];
            const float4 c = r4[2*d+2], e = r4[2*d+3];
            ya.x += fmaxf(a.x*f[0].x + a.y*f[1].x + a.z*f[2].x + a.w*f[3].x + b.x*f[4].x + b.y*f[5].x + b.z, 0.f) * b.w;
            ya.y += fmaxf(a.x*f[0].y + a.y*f[1].y + a.z*f[2].y + a.w*f[3].y + b.x*f[4].y + b.y*f[5].y + b.z, 0.f) * b.w;
            ya.z += fmaxf(a.x*f[0].z + a.y*f[1].z + a.z*f[2].z + a.w*f[3].z + b.x*f[4].z + b.y*f[5].z + b.z, 0.f) * b.w;
            ya.w += fmaxf(a.x*f[0].w + a.y*f[1].w + a.z*f[2].w + a.w*f[3].w + b.x*f[4].w + b.y*f[5].w + b.z, 0.f) * b.w;
            yb.x += fmaxf(c.x*f[0].x + c.y*f[1].x + c.z*f[2].x + c.w*f[3].x + e.x*f[4].x + e.y*f[5].x + e.z, 0.f) * e.w;
            yb.y += fmaxf(c.x*f[0].y + c.y*f[1].y + c.z*f[2].y + c.w*f[3].y + e.x*f[4].y + e.y*f[5].y + e.z, 0.f) * e.w;
            yb.z += fmaxf(c.x*f[0].z + c.y*f[1].z + c.z*f[2].z + c.w*f[3].z + e.x*f[4].z + e.y*f[5].z + e.z, 0.f) * e.w;
            yb.w += fmaxf(c.x*f[0].w + c.y*f[1].w + c.z*f[2].w + c.w*f[3].w + e.x*f[4].w + e.y*f[5].w + e.z, 0.f) * e.w;
        }
    }
    const float yv[4] = { ya.x + yb.x, ya.y + yb.y, ya.z + yb.z, ya.w + yb.w };
#pragma unroll
    for (int g = 0; g < 4; ++g) {
        const int bm = bm0 + g;
        const int b_ = bm / MM, m = bm - b_ * MM;
        out[j * BLM + b_ * MLT + t * MM + m] = yv[g] + b2v;
    }
}

// ---------- num branches: prefix/suffix trick, G=4 series per wave ----------
// block = (grp-pair, r); wave wid: grp = grp0+(wid>>1), series (wid&1)*4 .. +3
template <int P, int N>
__device__ __forceinline__ void knum_body4(const float* __restrict__ xtg,
        const float* __restrict__ wt, const float* __restrict__ b1,
        const float* __restrict__ W2, const float* __restrict__ b2,
        int grp0, int r, int j, float* __restrict__ out) {
    const int t = threadIdx.x, wid = t >> 6, lane = t & 63;
    const int grp = grp0 + (wid >> 1);
    if (grp >= 55) return;
    const int g0 = (wid & 1) * 4;
    const float* xb = xtg + grp * 1680 + r * N * 8 + g0;   // uniform float4 at +q*8
    const float4 b1v = *(const float4*)&b1[lane * 4];
    const float4 w2v = *(const float4*)&W2[lane * 4];
    const float b2v = b2[0];
    const float* wl = wt + lane * 4;
    float4 A0 = b1v, A1 = b1v, A2 = b1v, A3 = b1v;
    float4 B0 = make_float4(0.f,0.f,0.f,0.f), B1 = B0, B2 = B0, B3 = B0;
#pragma unroll 2
    for (int q = 1; q < N; ++q) {                           // suffix build
        const float4 w = *(const float4*)(wl + (q - 1) * DM);
        const float4 xv = *(const float4*)(xb + q * 8);
        fma4(B0, w, xv.x); fma4(B1, w, xv.y); fma4(B2, w, xv.z); fma4(B3, w, xv.w);
    }
    constexpr int NFULL = N / 8, TAIL = N - NFULL * 8;      // N%8 != 0 for all branches
    for (int c = 0; c <= NFULL; ++c) {
        float y0[8], y1[8], y2[8], y3[8];
        const bool full = (c < NFULL);
#pragma unroll
        for (int i = 0; i < 8; ++i) {
            const int k = c * 8 + i;
            if (full || i < TAIL) {
                float hx, hy, hz, hw;
                hx = fmaxf(A0.x + B0.x, 0.f); hy = fmaxf(A0.y + B0.y, 0.f);
                hz = fmaxf(A0.z + B0.z, 0.f); hw = fmaxf(A0.w + B0.w, 0.f);
                y0[i] = hx * w2v.x + hy * w2v.y + hz * w2v.z + hw * w2v.w;
                hx = fmaxf(A1.x + B1.x, 0.f); hy = fmaxf(A1.y + B1.y, 0.f);
                hz = fmaxf(A1.z + B1.z, 0.f); hw = fmaxf(A1.w + B1.w, 0.f);
                y1[i] = hx * w2v.x + hy * w2v.y + hz * w2v.z + hw * w2v.w;
                hx = fmaxf(A2.x + B2.x, 0.f); hy = fmaxf(A2.y + B2.y, 0.f);
                hz = fmaxf(A2.z + B2.z, 0.f); hw = fmaxf(A2.w + B2.w, 0.f);
                y2[i] = hx * w2v.x + hy * w2v.y + hz * w2v.z + hw * w2v.w;
                hx = fmaxf(A3.x + B3.x, 0.f); hy = fmaxf(A3.y + B3.y, 0.f);
                hz = fmaxf(A3.z + B3.z, 0.f); hw = fmaxf(A3.w + B3.w, 0.f);
                y3[i] = hx * w2v.x + hy * w2v.y + hz * w2v.z + hw * w2v.w;
                if (full || i < TAIL - 1) {                 // update (k+1 < N)
                    const float4 w   = *(const float4*)(wl + k * DM);
                    const float4 xk  = *(const float4*)(xb + k * 8);
                    const float4 xk1 = *(const float4*)(xb + k * 8 + 8);
                    fma4(A0, w, xk.x);  fma4(A1, w, xk.y);  fma4(A2, w, xk.z);  fma4(A3, w, xk.w);
                    fms4(B0, w, xk1.x); fms4(B1, w, xk1.y); fms4(B2, w, xk1.z); fms4(B3, w, xk1.w);
                }
            } else { y0[i] = 0.f; y1[i] = 0.f; y2[i] = 0.f; y3[i] = 0.f; }
        }
        const float v0 = bfly8(y0, lane), v1 = bfly8(y1, lane);
        const float v2 = bfly8(y2, lane), v3 = bfly8(y3, lane);
        if (lane < 32) {
            const int k = c * 8 + (lane & 7);
            if (k < N) {
                const int s = lane >> 3;                    // series index 0..3
                const int bm = grp * 8 + g0 + s;
                const float val = ((s == 0) ? v0 : (s == 1) ? v1 : (s == 2) ? v2 : v3) + b2v;
                const int fi = (k * P + r) * NBM + bm;
                const int ob = fi / MLT, rem = fi - ob * MLT;
                const int om = rem / LL, ol = rem - om * LL;
                out[(3 + j) * BLM + ob * MLT + ol * MM + om] = val;
            }
        }
    }
}

// ---------- seq branches: G=8 series/block, q-chunked, butterfly epilogue ----------
template <int ISNUM, int P, int N>
__device__ __forceinline__ void kseq_body(const float* __restrict__ xtg,
        const float* __restrict__ w1tb, const float* __restrict__ b1,
        const float* __restrict__ W2, const float* __restrict__ b2,
        int grp, int qc, int slab, float* __restrict__ out) {
    constexpr int NROWS = ISNUM ? (N - 1) : (P - 1);
    const int t = threadIdx.x, wid = t >> 6, lane = t & 63;
    const float4 b1v = *(const float4*)&b1[lane * 4];
    const float* xg = xtg + grp * 1680;
    float b2r[6];
#pragma unroll
    for (int tt = 0; tt < 6; ++tt) b2r[tt] = b2[tt];
    const int bm = grp * 8 + (lane & 7);
    const int b_ = bm / MM, m = bm - b_ * MM;
    const int qe = (qc * 9 + 9 < 35) ? (qc * 9 + 9) : 35;
    for (int q = qc * 9 + wid; q < qe; q += 4) {
        int pivot, fix;
        if (ISNUM) { pivot = q / P; fix = q - pivot * P; }   // LOO over n cols, fixed row r
        else       { pivot = q / N; fix = q - pivot * N; }   // LOO over p rows, fixed col k
        float4 acc[8];
#pragma unroll
        for (int g = 0; g < 8; ++g) acc[g] = b1v;
        const float* wl = w1tb + lane * 4;
        for (int idx = 0; idx < NROWS; ++idx) {
            const int row = idx + (idx >= pivot);
            const int pos0 = ISNUM ? (fix * N + row) * 6 : (row * N + fix) * 6;
            const float* xp = xg + pos0 * 8;
#pragma unroll
            for (int tt = 0; tt < 6; ++tt) {
                const float4 xa = *(const float4*)(xp + tt * 8);
                const float4 xc = *(const float4*)(xp + tt * 8 + 4);
                const float4 w  = *(const float4*)wl; wl += DM;
                fma4(acc[0], w, xa.x); fma4(acc[1], w, xa.y);
                fma4(acc[2], w, xa.z); fma4(acc[3], w, xa.w);
                fma4(acc[4], w, xc.x); fma4(acc[5], w, xc.y);
                fma4(acc[6], w, xc.z); fma4(acc[7], w, xc.w);
            }
        }
#pragma unroll
        for (int g = 0; g < 8; ++g) {
            acc[g].x = fmaxf(acc[g].x, 0.f); acc[g].y = fmaxf(acc[g].y, 0.f);
            acc[g].z = fmaxf(acc[g].z, 0.f); acc[g].w = fmaxf(acc[g].w, 0.f);
        }
        const int c2 = q / 5, dd = q - c2 * 5;   // d0 = patch_seq[0] = 5 (ref hardcode)
#pragma unroll
        for (int h = 0; h < 2; ++h) {
            float yv0[8], yv1[8], yv2[8];
#pragma unroll
            for (int tt2 = 0; tt2 < 3; ++tt2) {
                const int tt = h * 3 + tt2;
                const float4 w2v = *(const float4*)&W2[tt * DM + lane * 4];
                float* yv = (tt2 == 0) ? yv0 : ((tt2 == 1) ? yv1 : yv2);
#pragma unroll
                for (int g = 0; g < 8; ++g)
                    yv[g] = acc[g].x * w2v.x + acc[g].y * w2v.y + acc[g].z * w2v.z + acc[g].w * w2v.w;
            }
            const float r0 = bfly8(yv0, lane);
            const float r1 = bfly8(yv1, lane);
            const float r2 = bfly8(yv2, lane);
            if (lane < 8) {
#pragma unroll
                for (int tt2 = 0; tt2 < 3; ++tt2) {
                    const int tt = h * 3 + tt2;
                    const int l = ISNUM ? (dd * 42 + c2 * 6 + tt) : (q * 6 + tt);
                    const float rv = (tt2 == 0) ? r0 : ((tt2 == 1) ? r1 : r2);
                    out[slab + b_ * MLT + l * MM + m] = rv + b2r[tt];
                }
            }
        }
    }
}

// ---------- fused main dispatch, class-ordered, longest-first ----------
// [0,420) knum G4 : branch0 84, branch1 140, branch2 196
// [420,1300) kseq : 4 classes x 220
// [1300,1630) ksize G4 : 3 branches x 110
__global__ __launch_bounds__(256) void kfused(const float* __restrict__ xtg,
        const float* __restrict__ w1t, const float* __restrict__ recs,
        const float* __restrict__ b2s0, const float* __restrict__ b2s1, const float* __restrict__ b2s2,
        const float* __restrict__ nb1_0, const float* __restrict__ nW2_0, const float* __restrict__ nb2_0,
        const float* __restrict__ nb1_1, const float* __restrict__ nW2_1, const float* __restrict__ nb2_1,
        const float* __restrict__ nb1_2, const float* __restrict__ nW2_2, const float* __restrict__ nb2_2,
        const float* __restrict__ ss1b0, const float* __restrict__ ss2W0, const float* __restrict__ ss2b0,
        const float* __restrict__ ss1b1, const float* __restrict__ ss2W1, const float* __restrict__ ss2b1,
        const float* __restrict__ ns1b0, const float* __restrict__ ns2W0, const float* __restrict__ ns2b0,
        const float* __restrict__ ns1b1, const float* __restrict__ ns2W1, const float* __restrict__ ns2b1,
        float* __restrict__ out) {
    const int blk = blockIdx.x;
    if (blk < 420) {
        if (blk < 84) {
            const int r = blk % 3, grp0 = (blk / 3) * 2;
            knum_body4<3, 70>(xtg, w1t,            nb1_0, nW2_0, nb2_0, grp0, r, 0, out);
        } else if (blk < 224) {
            const int bn = blk - 84;
            const int r = bn % 5, grp0 = (bn / 5) * 2;
            knum_body4<5, 42>(xtg, w1t + 69 * DM,  nb1_1, nW2_1, nb2_1, grp0, r, 1, out);
        } else {
            const int bn = blk - 224;
            const int r = bn % 7, grp0 = (bn / 7) * 2;
            knum_body4<7, 30>(xtg, w1t + 110 * DM, nb1_2, nW2_2, nb2_2, grp0, r, 2, out);
        }
    } else if (blk < 1300) {
        const int bs = blk - 420;                  // [0, 880)
        const int tc = bs / 220, rem = bs - tc * 220;
        const int grp = rem >> 2, qc = rem & 3;
        if (tc == 0)      kseq_body<0, 5, 7>(xtg, w1t + 139 * DM, ss1b0, ss2W0, ss2b0, grp, qc, 6 * BLM, out);
        else if (tc == 1) kseq_body<0, 7, 5>(xtg, w1t + 163 * DM, ss1b1, ss2W1, ss2b1, grp, qc, 7 * BLM, out);
        else if (tc == 2) kseq_body<1, 5, 7>(xtg, w1t + 199 * DM, ns1b0, ns2W0, ns2b0, grp, qc, 8 * BLM, out);
        else              kseq_body<1, 7, 5>(xtg, w1t + 235 * DM, ns1b1, ns2W1, ns2b1, grp, qc, 9 * BLM, out);
    } else {
        const int bs = blk - 1300;                 // [0, 330)
        const int j = bs / 110, rel = bs - j * 110;
        const int bm0 = rel * 4;
        if (j == 0)      ksize_body4<2>(xtg, recs,        b2s0, bm0, 0, out);
        else if (j == 1) ksize_body4<4>(xtg, recs + 1024, b2s1, bm0, 1, out);
        else             ksize_body4<6>(xtg, recs + 3072, b2s2, bm0, 2, out);
    }
}

extern "C" void kernel_launch(void* const* d_in, const int* in_sizes, int n_in,
                              void* d_out, int out_size, void* d_ws, size_t ws_size,
                              hipStream_t stream) {
    (void)in_sizes; (void)n_in; (void)out_size; (void)ws_size;
    const float* x = (const float*)d_in[0];
    const float *s1W[3], *s1b[3], *s2W[3], *s2b[3], *n1W[3], *n1b[3], *n2W[3], *n2b[3];
    for (int j = 0; j < 3; ++j) {
        int base = 1 + j * 8;
        s1W[j] = (const float*)d_in[base + 0]; s1b[j] = (const float*)d_in[base + 1];
        s2W[j] = (const float*)d_in[base + 2]; s2b[j] = (const float*)d_in[base + 3];
        n1W[j] = (const float*)d_in[base + 4]; n1b[j] = (const float*)d_in[base + 5];
        n2W[j] = (const float*)d_in[base + 6]; n2b[j] = (const float*)d_in[base + 7];
    }
    const float *ss1W[2], *ss1b[2], *ss2W[2], *ss2b[2], *ns1W[2], *ns1b[2], *ns2W[2], *ns2b[2];
    for (int j = 0; j < 2; ++j) {
        int base = 25 + j * 8;
        ss1W[j] = (const float*)d_in[base + 0]; ss1b[j] = (const float*)d_in[base + 1];
        ss2W[j] = (const float*)d_in[base + 2]; ss2b[j] = (const float*)d_in[base + 3];
        ns1W[j] = (const float*)d_in[base + 4]; ns1b[j] = (const float*)d_in[base + 5];
        ns2W[j] = (const float*)d_in[base + 6]; ns2b[j] = (const float*)d_in[base + 7];
    }
    float* out  = (float*)d_out;
    float* xtg  = (float*)d_ws + XTG_OFF;
    float* w1t  = (float*)d_ws + W1T_OFF;
    float* recs = (float*)d_ws + REC_OFF;

    kprep<<<334, 256, 0, stream>>>(x,
        n1W[0], n1W[1], n1W[2],
        ss1W[0], ss1W[1], ns1W[0], ns1W[1],
        s1W[0], s1b[0], s2W[0],
        s1W[1], s1b[1], s2W[1],
        s1W[2], s1b[2], s2W[2],
        xtg, w1t, recs);
    kfused<<<1630, 256, 0, stream>>>(xtg, w1t, recs,
        s2b[0], s2b[1], s2b[2],
        n1b[0], n2W[0], n2b[0],
        n1b[1], n2W[1], n2b[1],
        n1b[2], n2W[2], n2b[2],
        ss1b[0], ss2W[0], ss2b[0],
        ss1b[1], ss2W[1], ss2b[1],
        ns1b[0], ns2W[0], ns2b[0],
        ns1b[1], ns2W[1], ns2b[1], out);
}

// Round 7
// 226.295 us; speedup vs baseline: 1.1566x; 1.1566x over previous
//
#include <hip/hip_runtime.h>

#define LL  210      // window length
#define MM  55       // channels
#define NBM 440      // B*M
#define DM  256      // d_model
#define MLT 11550    // MM*LL
#define BLM 92400    // B*LL*MM (one output slab)

// ws layout (floats):
#define XTG_OFF  0        // 55 grps * 210 pos * 8 series = 92400
#define W1T_OFF  92400    // 259 transposed cols * 256 = 66304
#define REC_OFF  158704   // ksize packed records = 5120
// w1t column offsets: num0=0(69), num1=69(41), num2=110(29),
//                     ss0=139(24), ss1=163(36), ns0=199(36), ns1=235(24)

__device__ __forceinline__ void fma4(float4& a, const float4 w, const float s) {
    a.x += w.x * s; a.y += w.y * s; a.z += w.z * s; a.w += w.w * s;
}
__device__ __forceinline__ void fms4(float4& a, const float4 w, const float s) {
    a.x -= w.x * s; a.y -= w.y * s; a.z -= w.z * s; a.w -= w.w * s;
}

// 8 simultaneous 64-lane reductions: returns sum over all lanes of y[lane&7]
__device__ __forceinline__ float bfly8(const float y[8], const int lane) {
    float z[4];
#pragma unroll
    for (int i = 0; i < 4; ++i) {
        float snd = (lane & 1) ? y[2*i] : y[2*i+1];
        float rcv = __shfl_xor(snd, 1, 64);
        z[i] = ((lane & 1) ? y[2*i+1] : y[2*i]) + rcv;
    }
    float u[2];
#pragma unroll
    for (int i = 0; i < 2; ++i) {
        float snd = (lane & 2) ? z[2*i] : z[2*i+1];
        float rcv = __shfl_xor(snd, 2, 64);
        u[i] = ((lane & 2) ? z[2*i+1] : z[2*i]) + rcv;
    }
    {
        float snd = (lane & 4) ? u[0] : u[1];
        float rcv = __shfl_xor(snd, 4, 64);
        float w = ((lane & 4) ? u[1] : u[0]) + rcv;
        w += __shfl_xor(w, 8, 64);
        w += __shfl_xor(w, 16, 64);
        w += __shfl_xor(w, 32, 64);
        return w;
    }
}

// ---------- prep: RevIN (grp-tiled, coalesced) -> xtg; transpose W1s; pack records ----------
__global__ __launch_bounds__(256) void kprep(
        const float* __restrict__ x,
        const float* __restrict__ nw0, const float* __restrict__ nw1, const float* __restrict__ nw2,
        const float* __restrict__ ssw0, const float* __restrict__ ssw1,
        const float* __restrict__ nsw0, const float* __restrict__ nsw1,
        const float* __restrict__ s1W0, const float* __restrict__ s1b0, const float* __restrict__ s2W0,
        const float* __restrict__ s1W1, const float* __restrict__ s1b1, const float* __restrict__ s2W1,
        const float* __restrict__ s1W2, const float* __restrict__ s1b2, const float* __restrict__ s2W2,
        float* __restrict__ xtg, float* __restrict__ w1t, float* __restrict__ recs) {
    const int t = threadIdx.x;
    const int blk = blockIdx.x;
    if (blk < 55) {
        // one grp of 8 series; thread = (li, mi); values kept in registers
        const int mi = t & 7, li = t >> 3;           // li in [0,32)
        const int bm = blk * 8 + mi;
        const int b = bm / MM, m = bm - b * MM;
        const float* xp = x + b * MLT + m;
        float vr[7], s1 = 0.f, s2 = 0.f;
#pragma unroll
        for (int it = 0; it < 7; ++it) {
            const int l = li + 32 * it;
            const float v = (l < LL) ? xp[l * MM] : 0.f;
            vr[it] = v; s1 += v; s2 += v * v;
        }
        s1 += __shfl_xor(s1, 8, 64);  s2 += __shfl_xor(s2, 8, 64);
        s1 += __shfl_xor(s1, 16, 64); s2 += __shfl_xor(s2, 16, 64);
        s1 += __shfl_xor(s1, 32, 64); s2 += __shfl_xor(s2, 32, 64);
        __shared__ float red[2][4][8];
        const int wid = t >> 6, lane = t & 63;
        if (lane < 8) { red[0][wid][lane] = s1; red[1][wid][lane] = s2; }
        __syncthreads();
        const float S1 = red[0][0][mi] + red[0][1][mi] + red[0][2][mi] + red[0][3][mi];
        const float S2 = red[1][0][mi] + red[1][1][mi] + red[1][2][mi] + red[1][3][mi];
        const float mean = S1 * (1.f / 210.f);
        const float inv = rsqrtf(S2 * (1.f / 210.f) - mean * mean + 1e-5f);
        float* xo = xtg + blk * 1680 + mi;
#pragma unroll
        for (int it = 0; it < 7; ++it) {
            const int l = li + 32 * it;
            if (l < LL) xo[l * 8] = (vr[it] - mean) * inv;
        }
    } else if (blk < 55 + 259) {
        const int e = (blk - 55) * 256 + t;   // [0, 259*256)
        const int cg = e >> 8, d = e & 255;
        const float* src; int ind, c;
        if (cg < 69)       { src = nw0;  ind = 69; c = cg; }
        else if (cg < 110) { src = nw1;  ind = 41; c = cg - 69; }
        else if (cg < 139) { src = nw2;  ind = 29; c = cg - 110; }
        else if (cg < 163) { src = ssw0; ind = 24; c = cg - 139; }
        else if (cg < 199) { src = ssw1; ind = 36; c = cg - 163; }
        else if (cg < 235) { src = nsw0; ind = 36; c = cg - 199; }
        else               { src = nsw1; ind = 24; c = cg - 235; }
        w1t[cg * DM + d] = src[d * ind + c];
    } else {
        const int e = (blk - 55 - 259) * 256 + t;   // [0, 5120)
        float v;
        if (e < 1024) {
            int d = e >> 2, c = e & 3;
            v = (c < 2) ? s1W0[d * 2 + c] : (c == 2 ? s1b0[d] : s2W0[d]);
        } else if (e < 3072) {
            int rel = e - 1024, d = rel >> 3, c = rel & 7;
            v = (c < 4) ? s1W1[d * 4 + c] : (c == 4 ? s1b1[d] : (c == 5 ? s2W1[d] : 0.f));
        } else {
            int rel = e - 3072, d = rel >> 3, c = rel & 7;
            v = (c < 6) ? s1W2[d * 6 + c] : (c == 6 ? s1b2[d] : s2W2[d]);
        }
        recs[e] = v;
    }
}

// ---------- size branches: thread-per-output, dual accumulators (R4-proven) ----------
template <int IND>
__device__ __forceinline__ void ksize_body(const float* __restrict__ xtg,
        const float* __restrict__ rec, const float* __restrict__ b2,
        int bm, int j, float* __restrict__ out) {
    constexpr int N = LL / (IND + 1);
    const int t = threadIdx.x;
    if (t >= LL) return;
    const float* xs = xtg + (bm >> 3) * 1680 + (bm & 7);
    const int i = t / N, k = t - i * N;
    float f[IND];
#pragma unroll
    for (int idx = 0; idx < IND; ++idx) {
        int row = idx + (idx >= i);
        f[idx] = xs[(row * N + k) * 8];
    }
    float y0 = b2[0], y1 = 0.f;
    const float4* r4 = (const float4*)rec;
    if constexpr (IND == 2) {
#pragma unroll 8
        for (int d = 0; d < DM; d += 2) {
            const float4 a = r4[d], b = r4[d + 1];
            y0 += fmaxf(a.x * f[0] + a.y * f[1] + a.z, 0.f) * a.w;
            y1 += fmaxf(b.x * f[0] + b.y * f[1] + b.z, 0.f) * b.w;
        }
    } else if constexpr (IND == 4) {
#pragma unroll 8
        for (int d = 0; d < DM; d += 2) {
            const float4 a = r4[2*d], b = r4[2*d+1];
            const float4 c = r4[2*d+2], e = r4[2*d+3];
            y0 += fmaxf(a.x*f[0] + a.y*f[1] + a.z*f[2] + a.w*f[3] + b.x, 0.f) * b.y;
            y1 += fmaxf(c.x*f[0] + c.y*f[1] + c.z*f[2] + c.w*f[3] + e.x, 0.f) * e.y;
        }
    } else {
#pragma unroll 8
        for (int d = 0; d < DM; d += 2) {
            const float4 a = r4[2*d], b = r4[2*d+1];
            const float4 c = r4[2*d+2], e = r4[2*d+3];
            y0 += fmaxf(a.x*f[0] + a.y*f[1] + a.z*f[2] + a.w*f[3] + b.x*f[4] + b.y*f[5] + b.z, 0.f) * b.w;
            y1 += fmaxf(c.x*f[0] + c.y*f[1] + c.z*f[2] + c.w*f[3] + e.x*f[4] + e.y*f[5] + e.z, 0.f) * e.w;
        }
    }
    const int b_ = bm / MM, m = bm - b_ * MM;
    out[j * BLM + b_ * MLT + t * MM + m] = y0 + y1;
}

// ---------- num branches: prefix/suffix trick, k-range HALF-split across blocks ----------
template <int P, int N, int HALF>
__device__ __forceinline__ void knum_bodyH(const float* __restrict__ xtg,
        const float* __restrict__ wt, const float* __restrict__ b1,
        const float* __restrict__ W2, const float* __restrict__ b2,
        int grp, int r, int j, float* __restrict__ out) {
    constexpr int KS  = HALF ? (N / 2) : 0;
    constexpr int KE  = HALF ? N : (N / 2);
    constexpr int CNT = KE - KS;
    const int t = threadIdx.x, wid = t >> 6, lane = t & 63;
    const int g0 = wid * 2;
    const float* xb = xtg + grp * 1680 + r * N * 8 + g0;   // uniform float2 at +q*8
    const float4 b1v = *(const float4*)&b1[lane * 4];
    const float4 w2v = *(const float4*)&W2[lane * 4];
    const float b2v = b2[0];
    const float* wl = wt + lane * 4;
    float4 A0 = b1v, A1 = b1v;                              // A[KS] = b1 + sum_{q<KS} w[q] x[q]
    float4 B0 = make_float4(0.f,0.f,0.f,0.f), B1 = B0;      // B[KS] = sum_{q>KS} w[q-1] x[q]
#pragma unroll 4
    for (int q = 0; q < KS; ++q) {
        const float4 w = *(const float4*)(wl + q * DM);
        const float2 xv = *(const float2*)(xb + q * 8);
        fma4(A0, w, xv.x); fma4(A1, w, xv.y);
    }
#pragma unroll 4
    for (int q = KS + 1; q < N; ++q) {
        const float4 w = *(const float4*)(wl + (q - 1) * DM);
        const float2 xv = *(const float2*)(xb + q * 8);
        fma4(B0, w, xv.x); fma4(B1, w, xv.y);
    }
    constexpr int NFULL = CNT / 8, TAIL = CNT - NFULL * 8;  // TAIL != 0 for all branches
    for (int c = 0; c <= NFULL; ++c) {
        float y0[8], y1[8];
        const bool full = (c < NFULL);
#pragma unroll
        for (int i = 0; i < 8; ++i) {
            const int k = KS + c * 8 + i;
            if (full || i < TAIL) {
                float hx = fmaxf(A0.x + B0.x, 0.f), hy = fmaxf(A0.y + B0.y, 0.f);
                float hz = fmaxf(A0.z + B0.z, 0.f), hw = fmaxf(A0.w + B0.w, 0.f);
                y0[i] = hx * w2v.x + hy * w2v.y + hz * w2v.z + hw * w2v.w;
                hx = fmaxf(A1.x + B1.x, 0.f); hy = fmaxf(A1.y + B1.y, 0.f);
                hz = fmaxf(A1.z + B1.z, 0.f); hw = fmaxf(A1.w + B1.w, 0.f);
                y1[i] = hx * w2v.x + hy * w2v.y + hz * w2v.z + hw * w2v.w;
                if (full || i < TAIL - 1) {                 // update (k+1 < KE)
                    const float4 w = *(const float4*)(wl + k * DM);
                    const float2 xk  = *(const float2*)(xb + k * 8);
                    const float2 xk1 = *(const float2*)(xb + k * 8 + 8);
                    fma4(A0, w, xk.x);  fma4(A1, w, xk.y);
                    fms4(B0, w, xk1.x); fms4(B1, w, xk1.y);
                }
            } else { y0[i] = 0.f; y1[i] = 0.f; }
        }
        const float v0 = bfly8(y0, lane), v1 = bfly8(y1, lane);
        if (lane < 16) {
            const int krel = c * 8 + (lane & 7);
            if (krel < CNT) {
                const int k = KS + krel;
                const int bm = grp * 8 + g0 + (lane >> 3);
                const float val = ((lane < 8) ? v0 : v1) + b2v;
                const int fi = (k * P + r) * NBM + bm;
                const int ob = fi / MLT, rem = fi - ob * MLT;
                const int om = rem / LL, ol = rem - om * LL;
                out[(3 + j) * BLM + ob * MLT + ol * MM + om] = val;
            }
        }
    }
}

// ---------- seq branches: G=8 series/block, 5-q chunks, butterfly epilogue ----------
template <int ISNUM, int P, int N>
__device__ __forceinline__ void kseq_body(const float* __restrict__ xtg,
        const float* __restrict__ w1tb, const float* __restrict__ b1,
        const float* __restrict__ W2, const float* __restrict__ b2,
        int grp, int qc, int slab, float* __restrict__ out) {
    constexpr int NROWS = ISNUM ? (N - 1) : (P - 1);
    const int t = threadIdx.x, wid = t >> 6, lane = t & 63;
    const float4 b1v = *(const float4*)&b1[lane * 4];
    const float* xg = xtg + grp * 1680;
    float b2r[6];
#pragma unroll
    for (int tt = 0; tt < 6; ++tt) b2r[tt] = b2[tt];
    const int bm = grp * 8 + (lane & 7);
    const int b_ = bm / MM, m = bm - b_ * MM;
    const int qs = qc * 5;                          // 35 = 7 chunks x 5
    for (int q = qs + wid; q < qs + 5; q += 4) {
        int pivot, fix;
        if (ISNUM) { pivot = q / P; fix = q - pivot * P; }   // LOO over n cols, fixed row r
        else       { pivot = q / N; fix = q - pivot * N; }   // LOO over p rows, fixed col k
        float4 acc[8];
#pragma unroll
        for (int g = 0; g < 8; ++g) acc[g] = b1v;
        const float* wl = w1tb + lane * 4;
        for (int idx = 0; idx < NROWS; ++idx) {
            const int row = idx + (idx >= pivot);
            const int pos0 = ISNUM ? (fix * N + row) * 6 : (row * N + fix) * 6;
            const float* xp = xg + pos0 * 8;
#pragma unroll
            for (int tt = 0; tt < 6; ++tt) {
                const float4 xa = *(const float4*)(xp + tt * 8);
                const float4 xc = *(const float4*)(xp + tt * 8 + 4);
                const float4 w  = *(const float4*)wl; wl += DM;
                fma4(acc[0], w, xa.x); fma4(acc[1], w, xa.y);
                fma4(acc[2], w, xa.z); fma4(acc[3], w, xa.w);
                fma4(acc[4], w, xc.x); fma4(acc[5], w, xc.y);
                fma4(acc[6], w, xc.z); fma4(acc[7], w, xc.w);
            }
        }
#pragma unroll
        for (int g = 0; g < 8; ++g) {
            acc[g].x = fmaxf(acc[g].x, 0.f); acc[g].y = fmaxf(acc[g].y, 0.f);
            acc[g].z = fmaxf(acc[g].z, 0.f); acc[g].w = fmaxf(acc[g].w, 0.f);
        }
        const int c2 = q / 5, dd = q - c2 * 5;   // d0 = patch_seq[0] = 5 (ref hardcode)
#pragma unroll
        for (int h = 0; h < 2; ++h) {
            float yv0[8], yv1[8], yv2[8];
#pragma unroll
            for (int tt2 = 0; tt2 < 3; ++tt2) {
                const int tt = h * 3 + tt2;
                const float4 w2v = *(const float4*)&W2[tt * DM + lane * 4];
                float* yv = (tt2 == 0) ? yv0 : ((tt2 == 1) ? yv1 : yv2);
#pragma unroll
                for (int g = 0; g < 8; ++g)
                    yv[g] = acc[g].x * w2v.x + acc[g].y * w2v.y + acc[g].z * w2v.z + acc[g].w * w2v.w;
            }
            const float r0 = bfly8(yv0, lane);
            const float r1 = bfly8(yv1, lane);
            const float r2 = bfly8(yv2, lane);
            if (lane < 8) {
#pragma unroll
                for (int tt2 = 0; tt2 < 3; ++tt2) {
                    const int tt = h * 3 + tt2;
                    const int l = ISNUM ? (dd * 42 + c2 * 6 + tt) : (q * 6 + tt);
                    const float rv = (tt2 == 0) ? r0 : ((tt2 == 1) ? r1 : r2);
                    out[slab + b_ * MLT + l * MM + m] = rv + b2r[tt];
                }
            }
        }
    }
}

// ---------- fused main dispatch, class-ordered (R4-proven), max block count ----------
// [0,1320) ksize ; [1320,2970) knum half-split ; [2970,4510) kseq 5-q chunks
__global__ __launch_bounds__(256) void kfused(const float* __restrict__ xtg,
        const float* __restrict__ w1t, const float* __restrict__ recs,
        const float* __restrict__ b2s0, const float* __restrict__ b2s1, const float* __restrict__ b2s2,
        const float* __restrict__ nb1_0, const float* __restrict__ nW2_0, const float* __restrict__ nb2_0,
        const float* __restrict__ nb1_1, const float* __restrict__ nW2_1, const float* __restrict__ nb2_1,
        const float* __restrict__ nb1_2, const float* __restrict__ nW2_2, const float* __restrict__ nb2_2,
        const float* __restrict__ ss1b0, const float* __restrict__ ss2W0, const float* __restrict__ ss2b0,
        const float* __restrict__ ss1b1, const float* __restrict__ ss2W1, const float* __restrict__ ss2b1,
        const float* __restrict__ ns1b0, const float* __restrict__ ns2W0, const float* __restrict__ ns2b0,
        const float* __restrict__ ns1b1, const float* __restrict__ ns2W1, const float* __restrict__ ns2b1,
        float* __restrict__ out) {
    const int blk = blockIdx.x;
    if (blk < 1320) {
        if (blk < NBM)          ksize_body<2>(xtg, recs,        b2s0, blk,           0, out);
        else if (blk < 2 * NBM) ksize_body<4>(xtg, recs + 1024, b2s1, blk - NBM,     1, out);
        else                    ksize_body<6>(xtg, recs + 3072, b2s2, blk - 2 * NBM, 2, out);
    } else if (blk < 2970) {
        const int bn = blk - 1320;                 // [0, 1650)
        if (bn < 330) {
            const int pair = bn >> 1, half = bn & 1;
            const int grp = pair / 3, r = pair - grp * 3;
            if (half == 0) knum_bodyH<3, 70, 0>(xtg, w1t, nb1_0, nW2_0, nb2_0, grp, r, 0, out);
            else           knum_bodyH<3, 70, 1>(xtg, w1t, nb1_0, nW2_0, nb2_0, grp, r, 0, out);
        } else if (bn < 880) {
            const int x = bn - 330;
            const int pair = x >> 1, half = x & 1;
            const int grp = pair / 5, r = pair - grp * 5;
            if (half == 0) knum_bodyH<5, 42, 0>(xtg, w1t + 69 * DM, nb1_1, nW2_1, nb2_1, grp, r, 1, out);
            else           knum_bodyH<5, 42, 1>(xtg, w1t + 69 * DM, nb1_1, nW2_1, nb2_1, grp, r, 1, out);
        } else {
            const int x = bn - 880;
            const int pair = x >> 1, half = x & 1;
            const int grp = pair / 7, r = pair - grp * 7;
            if (half == 0) knum_bodyH<7, 30, 0>(xtg, w1t + 110 * DM, nb1_2, nW2_2, nb2_2, grp, r, 2, out);
            else           knum_bodyH<7, 30, 1>(xtg, w1t + 110 * DM, nb1_2, nW2_2, nb2_2, grp, r, 2, out);
        }
    } else {
        const int bs = blk - 2970;                 // [0, 1540)
        const int tc = bs / 385, rem = bs - tc * 385;
        const int grp = rem / 7, qc = rem - grp * 7;
        if (tc == 0)      kseq_body<0, 5, 7>(xtg, w1t + 139 * DM, ss1b0, ss2W0, ss2b0, grp, qc, 6 * BLM, out);
        else if (tc == 1) kseq_body<0, 7, 5>(xtg, w1t + 163 * DM, ss1b1, ss2W1, ss2b1, grp, qc, 7 * BLM, out);
        else if (tc == 2) kseq_body<1, 5, 7>(xtg, w1t + 199 * DM, ns1b0, ns2W0, ns2b0, grp, qc, 8 * BLM, out);
        else              kseq_body<1, 7, 5>(xtg, w1t + 235 * DM, ns1b1, ns2W1, ns2b1, grp, qc, 9 * BLM, out);
    }
}

extern "C" void kernel_launch(void* const* d_in, const int* in_sizes, int n_in,
                              void* d_out, int out_size, void* d_ws, size_t ws_size,
                              hipStream_t stream) {
    (void)in_sizes; (void)n_in; (void)out_size; (void)ws_size;
    const float* x = (const float*)d_in[0];
    const float *s1W[3], *s1b[3], *s2W[3], *s2b[3], *n1W[3], *n1b[3], *n2W[3], *n2b[3];
    for (int j = 0; j < 3; ++j) {
        int base = 1 + j * 8;
        s1W[j] = (const float*)d_in[base + 0]; s1b[j] = (const float*)d_in[base + 1];
        s2W[j] = (const float*)d_in[base + 2]; s2b[j] = (const float*)d_in[base + 3];
        n1W[j] = (const float*)d_in[base + 4]; n1b[j] = (const float*)d_in[base + 5];
        n2W[j] = (const float*)d_in[base + 6]; n2b[j] = (const float*)d_in[base + 7];
    }
    const float *ss1W[2], *ss1b[2], *ss2W[2], *ss2b[2], *ns1W[2], *ns1b[2], *ns2W[2], *ns2b[2];
    for (int j = 0; j < 2; ++j) {
        int base = 25 + j * 8;
        ss1W[j] = (const float*)d_in[base + 0]; ss1b[j] = (const float*)d_in[base + 1];
        ss2W[j] = (const float*)d_in[base + 2]; ss2b[j] = (const float*)d_in[base + 3];
        ns1W[j] = (const float*)d_in[base + 4]; ns1b[j] = (const float*)d_in[base + 5];
        ns2W[j] = (const float*)d_in[base + 6]; ns2b[j] = (const float*)d_in[base + 7];
    }
    float* out  = (float*)d_out;
    float* xtg  = (float*)d_ws + XTG_OFF;
    float* w1t  = (float*)d_ws + W1T_OFF;
    float* recs = (float*)d_ws + REC_OFF;

    kprep<<<334, 256, 0, stream>>>(x,
        n1W[0], n1W[1], n1W[2],
        ss1W[0], ss1W[1], ns1W[0], ns1W[1],
        s1W[0], s1b[0], s2W[0],
        s1W[1], s1b[1], s2W[1],
        s1W[2], s1b[2], s2W[2],
        xtg, w1t, recs);
    kfused<<<4510, 256, 0, stream>>>(xtg, w1t, recs,
        s2b[0], s2b[1], s2b[2],
        n1b[0], n2W[0], n2b[0],
        n1b[1], n2W[1], n2b[1],
        n1b[2], n2W[2], n2b[2],
        ss1b[0], ss2W[0], ss2b[0],
        ss1b[1], ss2W[1], ss2b[1],
        ns1b[0], ns2W[0], ns2b[0],
        ns1b[1], ns2W[1], ns2b[1], out);
}